// Round 4
// baseline (519.036 us; speedup 1.0000x reference)
//
#include <hip/hip_runtime.h>

constexpr int B  = 2;
constexpr int NH = 8;
constexpr int L  = 512;
constexpr int D  = 64;
constexpr float INV_TEMP = 0.125f;   // 1/sqrt(D) = 1/8
constexpr int SCP = 520;             // sc row stride (pad 8 breaks 512 aliasing)

// ---------------------------------------------------------------------------
// K1: S1[b,h,i,j] = (q[b,h,i,:]/8) . k[b,h,j,:]  -> d_ws   (proven in R3)
// grid (16, L/64, L/128), block 256.
// ---------------------------------------------------------------------------
__global__ __launch_bounds__(256) void k1_qk(const float* __restrict__ q,
                                             const float* __restrict__ k,
                                             float* __restrict__ s1) {
  const int bh = blockIdx.x, it = blockIdx.y, jt = blockIdx.z;
  __shared__ float Qs[64][68];
  __shared__ float Ks[128][68];
  const int t = threadIdx.x;
  const float* qb = q + ((size_t)bh * L + it * 64) * D;
  const float* kb = k + ((size_t)bh * L + jt * 128) * D;
#pragma unroll
  for (int n0 = 0; n0 < 4; ++n0) {
    int n = t + (n0 << 8);
    int r = n >> 4, c = (n & 15) << 2;
    float4 a = *(const float4*)(qb + (size_t)r * D + c);
    a.x *= INV_TEMP; a.y *= INV_TEMP; a.z *= INV_TEMP; a.w *= INV_TEMP;
    *(float4*)&Qs[r][c] = a;
  }
#pragma unroll
  for (int n0 = 0; n0 < 8; ++n0) {
    int n = t + (n0 << 8);
    int r = n >> 4, c = (n & 15) << 2;
    *(float4*)&Ks[r][c] = *(const float4*)(kb + (size_t)r * D + c);
  }
  __syncthreads();
  const int i0 = t >> 4, j0 = t & 15;
  float acc[4][8] = {};
#pragma unroll 1
  for (int kc = 0; kc < 64; kc += 4) {
    float4 a[4], b[8];
#pragma unroll
    for (int m = 0; m < 4; ++m) a[m] = *(const float4*)&Qs[i0 + 16 * m][kc];
#pragma unroll
    for (int n = 0; n < 8; ++n) b[n] = *(const float4*)&Ks[j0 + 16 * n][kc];
#pragma unroll
    for (int m = 0; m < 4; ++m)
#pragma unroll
      for (int n = 0; n < 8; ++n)
        acc[m][n] = fmaf(a[m].x, b[n].x,
                    fmaf(a[m].y, b[n].y,
                    fmaf(a[m].z, b[n].z,
                    fmaf(a[m].w, b[n].w, acc[m][n]))));
  }
  float* sb = s1 + ((size_t)bh * L + it * 64) * L + jt * 128;
#pragma unroll
  for (int m = 0; m < 4; ++m) {
    float* srow = sb + (size_t)(i0 + 16 * m) * L;
#pragma unroll
    for (int n = 0; n < 8; ++n) srow[j0 + 16 * n] = acc[m][n];
  }
}

// ---------------------------------------------------------------------------
// K2: one block per (b,i), 256 threads, 4 waves; wave w owns j in [128w,128w+128).
// Lane mapping: h = lane>>3 (head), sub = lane&7.
//  A: sc[h][j] = s1 + q_hat[h].adj_k[b,i,j,:]  — full dot per lane, q in regs,
//     adj_k read once per block (8-row x 16B segments, 8-lane broadcast).
//  B: mask + softmax -> attn (global) + p (LDS).
//  C: out[h][d] = sum_j p*(v+adj_v), lane=(h, d-oct), float4 streams,
//     cross-wave reduce via obuf.
// ---------------------------------------------------------------------------
__global__ __launch_bounds__(256, 4) void k2_fused(
    const float* __restrict__ q, const float* __restrict__ v,
    const float* __restrict__ adj_k, const float* __restrict__ adj_v,
    const int* __restrict__ mask, const float* __restrict__ s1,
    float* __restrict__ out, float* __restrict__ attn) {
  const int b = blockIdx.x >> 9, i = blockIdx.x & (L - 1);
  const int t = threadIdx.x;
  const int wv = t >> 6, lane = t & 63;
  const int h = lane >> 3, sub = lane & 7;
  __shared__ float sc[NH * SCP];        // 16.3 KB
  __shared__ float obuf[4 * NH * D];    // 8 KB

  // q_hat for this lane's head: 16 quads, register-resident
  const float* qrow = q + (((size_t)b * NH + h) * L + i) * D;
  float4 qreg[16];
#pragma unroll
  for (int u = 0; u < 16; ++u) {
    float4 qv = *(const float4*)(qrow + 4 * u);
    qreg[u].x = qv.x * INV_TEMP; qreg[u].y = qv.y * INV_TEMP;
    qreg[u].z = qv.z * INV_TEMP; qreg[u].w = qv.w * INV_TEMP;
  }

  // ---------------- phase A: scores ----------------------------------------
  const float* akb = adj_k + ((size_t)b * L + i) * (size_t)L * D;
  const float* s1r = s1 + (((size_t)b * NH + h) * L + i) * L;
  const int jw = wv * 128;
  for (int c = 0; c < 16; c += 2) {     // 2 chunks in flight for ILP
    const int ja = jw + c * 8 + sub, jb = ja + 8;
    const float* ra = akb + (size_t)ja * D;
    const float* rb = akb + (size_t)jb * D;
    float accA = s1r[ja], accB = s1r[jb];
#pragma unroll 4
    for (int u = 0; u < 16; ++u) {
      float4 a = *(const float4*)(ra + 4 * u);
      float4 bq = *(const float4*)(rb + 4 * u);
      accA = fmaf(qreg[u].x, a.x, fmaf(qreg[u].y, a.y,
             fmaf(qreg[u].z, a.z, fmaf(qreg[u].w, a.w, accA))));
      accB = fmaf(qreg[u].x, bq.x, fmaf(qreg[u].y, bq.y,
             fmaf(qreg[u].z, bq.z, fmaf(qreg[u].w, bq.w, accB))));
    }
    sc[h * SCP + ja] = accA;            // banks (8h+j)%32: 2-way max (free)
    sc[h * SCP + jb] = accB;
  }
  __syncthreads();

  // ---------------- phase B: mask + softmax (32 lanes per head row) --------
  {
    const int hB = t >> 5, lB = t & 31;
    const int* mrow = mask + b * L;
    float* arow = attn + (((size_t)b * NH + hB) * L + i) * L;
    float vals[16];
    float mx = -3.4e38f;
#pragma unroll
    for (int m = 0; m < 16; ++m) {
      int jj = lB + (m << 5);
      float vsc = sc[hB * SCP + jj];
      vsc = (mrow[jj] == 0) ? -10000.0f : vsc;
      vals[m] = vsc;
      mx = fmaxf(mx, vsc);
    }
#pragma unroll
    for (int off = 16; off > 0; off >>= 1) mx = fmaxf(mx, __shfl_xor(mx, off, 32));
    float sum = 0.f;
#pragma unroll
    for (int m = 0; m < 16; ++m) { vals[m] = __expf(vals[m] - mx); sum += vals[m]; }
#pragma unroll
    for (int off = 16; off > 0; off >>= 1) sum += __shfl_xor(sum, off, 32);
    const float inv = 1.0f / sum;
#pragma unroll
    for (int m = 0; m < 16; ++m) {
      int jj = lB + (m << 5);
      float p = vals[m] * inv;
      arow[jj] = p;                     // only HBM pass for attn
      sc[hB * SCP + jj] = p;            // reuse for phase C
    }
  }
  __syncthreads();

  // ---------------- phase C: out = sum_j p * (v + adj_v) -------------------
  {
    const int d0 = sub * 8;             // this lane: head h, d in [d0, d0+8)
    const float* avb = adj_v + ((size_t)b * L + i) * (size_t)L * D + d0;
    const float* vb  = v + ((size_t)b * NH + h) * (size_t)L * D + d0;
    float4 acA = {0.f, 0.f, 0.f, 0.f}, acB = {0.f, 0.f, 0.f, 0.f};
    for (int j = jw; j < jw + 128; j += 2) {   // 2 j in flight for ILP
      float p0 = sc[h * SCP + j];
      float p1 = sc[h * SCP + j + 1];
      const float* a0 = avb + (size_t)j * D;
      const float* w0 = vb + (size_t)j * D;
      float4 av00 = *(const float4*)(a0);
      float4 av01 = *(const float4*)(a0 + 4);
      float4 vv00 = *(const float4*)(w0);
      float4 vv01 = *(const float4*)(w0 + 4);
      float4 av10 = *(const float4*)(a0 + D);
      float4 av11 = *(const float4*)(a0 + D + 4);
      float4 vv10 = *(const float4*)(w0 + D);
      float4 vv11 = *(const float4*)(w0 + D + 4);
      acA.x = fmaf(p0, av00.x + vv00.x, acA.x);
      acA.y = fmaf(p0, av00.y + vv00.y, acA.y);
      acA.z = fmaf(p0, av00.z + vv00.z, acA.z);
      acA.w = fmaf(p0, av00.w + vv00.w, acA.w);
      acB.x = fmaf(p0, av01.x + vv01.x, acB.x);
      acB.y = fmaf(p0, av01.y + vv01.y, acB.y);
      acB.z = fmaf(p0, av01.z + vv01.z, acB.z);
      acB.w = fmaf(p0, av01.w + vv01.w, acB.w);
      acA.x = fmaf(p1, av10.x + vv10.x, acA.x);
      acA.y = fmaf(p1, av10.y + vv10.y, acA.y);
      acA.z = fmaf(p1, av10.z + vv10.z, acA.z);
      acA.w = fmaf(p1, av10.w + vv10.w, acA.w);
      acB.x = fmaf(p1, av11.x + vv11.x, acB.x);
      acB.y = fmaf(p1, av11.y + vv11.y, acB.y);
      acB.z = fmaf(p1, av11.z + vv11.z, acB.z);
      acB.w = fmaf(p1, av11.w + vv11.w, acB.w);
    }
    *(float4*)&obuf[(wv * NH * D) + h * D + d0]     = acA;
    *(float4*)&obuf[(wv * NH * D) + h * D + d0 + 4] = acB;
  }
  __syncthreads();
  // cross-wave reduce + store: thread n covers outputs n, n+256
  for (int n = t; n < NH * D; n += 256) {
    float s = obuf[n] + obuf[NH * D + n] + obuf[2 * NH * D + n] + obuf[3 * NH * D + n];
    out[(((size_t)b * NH + (n >> 6)) * L + i) * D + (n & 63)] = s;
  }
}

// ---------------------------------------------------------------------------
extern "C" void kernel_launch(void* const* d_in, const int* in_sizes, int n_in,
                              void* d_out, int out_size, void* d_ws, size_t ws_size,
                              hipStream_t stream) {
  const float* q     = (const float*)d_in[0];
  const float* k     = (const float*)d_in[1];
  const float* v     = (const float*)d_in[2];
  const float* adj_k = (const float*)d_in[3];
  const float* adj_v = (const float*)d_in[4];
  const int*   mask  = (const int*)d_in[5];
  float* out  = (float*)d_out;
  float* attn = out + (size_t)B * NH * L * D;   // second output region
  float* s1   = (float*)d_ws;                   // B*NH*L*L fp32 = 16.8 MB

  dim3 g1(B * NH, L / 64, L / 128);
  k1_qk<<<g1, 256, 0, stream>>>(q, k, s1);
  k2_fused<<<B * L, 256, 0, stream>>>(q, v, adj_k, adj_v, mask, s1, out, attn);
}